// Round 10
// baseline (1264.949 us; speedup 1.0000x reference)
//
#include <hip/hip_runtime.h>

typedef unsigned short u16;
typedef u16 u16x8 __attribute__((ext_vector_type(8)));
typedef u16 u16x4 __attribute__((ext_vector_type(4)));
typedef __bf16 bf16x8 __attribute__((ext_vector_type(8)));
typedef float f32x4 __attribute__((ext_vector_type(4)));

#define Bn   4
#define Nn   3072
#define DIMn 768
#define Hn   3
#define HDn  256
#define BHn  12
#define Dn   262
#define EP   272      // e-rows padded to 17*16

__device__ __forceinline__ u16 f2bf(float f) {
    unsigned u = __builtin_bit_cast(unsigned, f);
    u += 0x7fffu + ((u >> 16) & 1u);
    return (u16)(u >> 16);
}
__device__ __forceinline__ float bf2f(u16 h) {
    unsigned u = ((unsigned)h) << 16;
    return __builtin_bit_cast(float, u);
}
__device__ __forceinline__ bf16x8 ld_frag16(const u16* p) {   // 16B-aligned read
    return *(const bf16x8*)p;
}
__device__ __forceinline__ bf16x8 ld_frag8(const u16* p) {    // 8B-aligned (2x b64)
    union { u16x4 h[2]; bf16x8 v; } u;
    u.h[0] = *(const u16x4*)p;
    u.h[1] = *(const u16x4*)(p + 4);
    return u.v;
}
#define MFMA(a,b,c) __builtin_amdgcn_mfma_f32_16x16x32_bf16(a, b, c, 0, 0, 0)

// ---------------------------------------------------------------------------
// K0: fp32 -> bf16 elementwise (x and W pre-conversion)
// ---------------------------------------------------------------------------
__global__ void to_bf16(const float* __restrict__ in, u16* __restrict__ out, int n8) {
    int i = blockIdx.x * blockDim.x + threadIdx.x;
    if (i >= n8) return;
    float4 a = *(const float4*)(in + (size_t)i*8);
    float4 b = *(const float4*)(in + (size_t)i*8 + 4);
    u16x8 o;
    o[0]=f2bf(a.x); o[1]=f2bf(a.y); o[2]=f2bf(a.z); o[3]=f2bf(a.w);
    o[4]=f2bf(b.x); o[5]=f2bf(b.y); o[6]=f2bf(b.z); o[7]=f2bf(b.w);
    *(u16x8*)(out + (size_t)i*8) = o;
}

// ---------------------------------------------------------------------------
// K1: qkv = x @ W_qkv^T via MFMA (bf16 inputs, register-prefetch pipeline).
// Writes qh/kh bf16 [bh][n][256] and vT bf16 [bh][272][3072] (transposed).
// ---------------------------------------------------------------------------
__global__ __launch_bounds__(256) void qkv_mfma(const u16* __restrict__ xb,
                                                const u16* __restrict__ Wb,
                                                u16* __restrict__ qh,
                                                u16* __restrict__ kh,
                                                u16* __restrict__ vT) {
    __shared__ u16 Xs[64*72];
    __shared__ u16 Ws[64*72];
    __shared__ u16 Cs[64*72];
    int tid = threadIdx.x;
    int w = tid >> 6, lane = tid & 63, quad = lane >> 4, l15 = lane & 15;
    int cb = blockIdx.x, rb = blockIdx.y;
    int r0 = rb * 64;
    int b_ = rb / 48;
    int n0 = (rb % 48) * 64;
    int which = cb / 12;             // 0:q 1:k 2:v
    int c0l = (cb % 12) * 64;        // col base within 768
    int h = c0l >> 8, hd0 = c0l & 255;
    int bh = b_ * Hn + h;
    int wr = w >> 1, wc = w & 1;
    const u16* xp = xb + (size_t)r0*DIMn;
    const u16* wp = Wb + (size_t)(which*768 + c0l)*DIMn;
    const int sr = tid >> 3, ssg = tid & 7;     // staging: rows sr+32i, seg ssg

    u16x8 xreg[2], wreg[2];
    #pragma unroll
    for (int i = 0; i < 2; ++i) {
        xreg[i] = *(const u16x8*)(xp + (size_t)(sr + 32*i)*DIMn + ssg*8);
        wreg[i] = *(const u16x8*)(wp + (size_t)(sr + 32*i)*DIMn + ssg*8);
    }

    f32x4 acc[2][2];
    #pragma unroll
    for (int i = 0; i < 2; ++i)
        #pragma unroll
        for (int j = 0; j < 2; ++j) acc[i][j] = (f32x4){0.f,0.f,0.f,0.f};

    for (int k0 = 0; k0 < DIMn; k0 += 64) {
        int k0n = (k0 + 64 < DIMn) ? k0 + 64 : 0;
        __syncthreads();
        #pragma unroll
        for (int i = 0; i < 2; ++i) {
            *(u16x8*)&Xs[(sr + 32*i)*72 + ssg*8] = xreg[i];
            *(u16x8*)&Ws[(sr + 32*i)*72 + ssg*8] = wreg[i];
        }
        __syncthreads();
        #pragma unroll
        for (int i = 0; i < 2; ++i) {
            xreg[i] = *(const u16x8*)(xp + (size_t)(sr + 32*i)*DIMn + k0n + ssg*8);
            wreg[i] = *(const u16x8*)(wp + (size_t)(sr + 32*i)*DIMn + k0n + ssg*8);
        }
        #pragma unroll
        for (int ks = 0; ks < 2; ++ks) {
            bf16x8 a0 = ld_frag16(&Xs[(wr*32 +  0 + l15)*72 + ks*32 + quad*8]);
            bf16x8 a1 = ld_frag16(&Xs[(wr*32 + 16 + l15)*72 + ks*32 + quad*8]);
            bf16x8 b0 = ld_frag16(&Ws[(wc*32 +  0 + l15)*72 + ks*32 + quad*8]);
            bf16x8 b1 = ld_frag16(&Ws[(wc*32 + 16 + l15)*72 + ks*32 + quad*8]);
            acc[0][0] = MFMA(a0, b0, acc[0][0]);
            acc[0][1] = MFMA(a0, b1, acc[0][1]);
            acc[1][0] = MFMA(a1, b0, acc[1][0]);
            acc[1][1] = MFMA(a1, b1, acc[1][1]);
        }
    }
    __syncthreads();
    // write C tiles to Cs (transposed for v)
    #pragma unroll
    for (int rt = 0; rt < 2; ++rt)
        #pragma unroll
        for (int ct = 0; ct < 2; ++ct)
            #pragma unroll
            for (int r = 0; r < 4; ++r) {
                int row = wr*32 + rt*16 + quad*4 + r;
                int col = wc*32 + ct*16 + l15;
                u16 v = f2bf(acc[rt][ct][r]);
                if (which < 2) Cs[row*72 + col] = v;
                else           Cs[col*72 + row] = v;
            }
    __syncthreads();
    #pragma unroll
    for (int i = 0; i < 2; ++i) {
        int u = tid + i*256;
        int row = u >> 3, seg = u & 7;
        u16x8 vv = *(const u16x8*)&Cs[row*72 + seg*8];
        if (which == 0)
            *(u16x8*)(qh + ((size_t)bh*Nn + n0 + row)*HDn + hd0 + seg*8) = vv;
        else if (which == 1)
            *(u16x8*)(kh + ((size_t)bh*Nn + n0 + row)*HDn + hd0 + seg*8) = vv;
        else
            *(u16x8*)(vT + ((size_t)bh*EP + hd0 + row)*Nn + n0 + seg*8) = vv;
    }
}

// ---------------------------------------------------------------------------
// K1b: positional rows 256..261 of vT; rows 262..271 get zero.
// ---------------------------------------------------------------------------
__global__ void pos_fill(u16* __restrict__ vT) {
    int idx = blockIdx.x * blockDim.x + threadIdx.x;   // over BH*16*N
    int bh = idx / (16*Nn);
    int rem = idx - bh*16*Nn;
    int row = rem / Nn;        // 0..15
    int n = rem - row*Nn;
    int gy = n % 48, gx = n / 48;
    float p3 = -1.0f + (2.0f/47.0f)*gy;
    float p4 = -1.0f + (2.0f/63.0f)*gx;
    float v = 0.f;
    if (row == 0) v = p3*p3;
    else if (row == 1) v = p4*p4;
    else if (row == 2) v = p3*p4;
    else if (row == 3) v = p3;
    else if (row == 4) v = p4;
    else if (row == 5) v = 1.0f;
    vT[((size_t)bh*EP + 256 + row)*Nn + n] = f2bf(v);
}

// ---------------------------------------------------------------------------
// K2 v5: barrier-free main loop. Q staged via LDS once (entry); K fragments
// loaded DIRECT from global with a half-chunk double-buffered register
// pipeline (kf0/kf1) — loads for half h+1 issued before computing half h,
// so ~300+ cyc of MFMA covers the L2 latency (R7's just-in-time loads
// didn't). No LDS traffic in the loop at all.
// R_part[mhalf][bh][n] exclusive; C_part[nb*2+wn][bh][m] exclusive.
// ---------------------------------------------------------------------------
__global__ __launch_bounds__(256, 2) void rc_mfma(const u16* __restrict__ qh,
                                                  const u16* __restrict__ kh,
                                                  float* __restrict__ R_part,
                                                  float* __restrict__ C_part) {
    __shared__ u16 Qs[64*264];            // Q staging only (entry)
    __shared__ float rbuf[2][2][64];      // [wm][nt][wn*32 + l15]
    int tid = threadIdx.x;
    int w = tid >> 6, lane = tid & 63, quad = lane >> 4, l15 = lane & 15;
    int bh = blockIdx.z;
    int nb = blockIdx.y;
    int n0 = nb * 64;
    int mhalf = blockIdx.x;               // 0 or 1
    const u16* qp = qh + ((size_t)bh*Nn + n0)*HDn;
    const u16* kp = kh + (size_t)bh*Nn*HDn;
    int wm = w & 1, wn = w >> 1;

    // stage Q tile via LDS once, preload fragments
    #pragma unroll
    for (int i = 0; i < 8; ++i) {
        int e = tid + i*256;
        int row = e >> 5, seg = e & 31;
        *(u16x8*)&Qs[row*264 + seg*8] = *(const u16x8*)(qp + (size_t)row*HDn + seg*8);
    }
    __syncthreads();
    bf16x8 qf[2][8];
    #pragma unroll
    for (int nt = 0; nt < 2; ++nt)
        #pragma unroll
        for (int ks = 0; ks < 8; ++ks)
            qf[nt][ks] = ld_frag16(&Qs[((2*wn+nt)*16 + l15)*264 + ks*32 + quad*8]);

    // per-wave K row bases (col offset quad*8 folded in)
    const u16* ka = kp + (size_t)((2*wm+0)*16 + l15)*HDn + quad*8;
    const u16* kb = kp + (size_t)((2*wm+1)*16 + l15)*HDn + quad*8;
    const int base = mhalf*(Nn/2);

    bf16x8 kf0[8], kf1[8];
    // init: kf0 <- (chunk 0, half 0)
    #pragma unroll
    for (int ksl = 0; ksl < 4; ++ksl) {
        kf0[2*ksl+0] = *(const bf16x8*)(ka + (size_t)base*HDn + ksl*32);
        kf0[2*ksl+1] = *(const bf16x8*)(kb + (size_t)base*HDn + ksl*32);
    }

    float* cpart = C_part + ((size_t)(nb*2 + wn)*BHn + bh)*Nn;
    float rAcc[2] = {0.f, 0.f};
    for (int mc = 0; mc < Nn/128; ++mc) {
        int m0 = base + mc*64;
        int m0n = base + ((mc + 1 < Nn/128) ? (mc + 1)*64 : 0);
        f32x4 sacc[2][2];
        #pragma unroll
        for (int i = 0; i < 2; ++i)
            #pragma unroll
            for (int j = 0; j < 2; ++j) sacc[i][j] = (f32x4){0.f,0.f,0.f,0.f};
        // prefetch kf1 <- (m0, half 1)
        #pragma unroll
        for (int ksl = 0; ksl < 4; ++ksl) {
            kf1[2*ksl+0] = *(const bf16x8*)(ka + (size_t)m0*HDn + (4+ksl)*32);
            kf1[2*ksl+1] = *(const bf16x8*)(kb + (size_t)m0*HDn + (4+ksl)*32);
        }
        // compute ks 0..3 with kf0
        #pragma unroll
        for (int ksl = 0; ksl < 4; ++ksl) {
            sacc[0][0] = MFMA(kf0[2*ksl+0], qf[0][ksl], sacc[0][0]);
            sacc[0][1] = MFMA(kf0[2*ksl+0], qf[1][ksl], sacc[0][1]);
            sacc[1][0] = MFMA(kf0[2*ksl+1], qf[0][ksl], sacc[1][0]);
            sacc[1][1] = MFMA(kf0[2*ksl+1], qf[1][ksl], sacc[1][1]);
        }
        // prefetch kf0 <- (next chunk, half 0)
        #pragma unroll
        for (int ksl = 0; ksl < 4; ++ksl) {
            kf0[2*ksl+0] = *(const bf16x8*)(ka + (size_t)m0n*HDn + ksl*32);
            kf0[2*ksl+1] = *(const bf16x8*)(kb + (size_t)m0n*HDn + ksl*32);
        }
        // compute ks 4..7 with kf1
        #pragma unroll
        for (int ksl = 0; ksl < 4; ++ksl) {
            sacc[0][0] = MFMA(kf1[2*ksl+0], qf[0][4+ksl], sacc[0][0]);
            sacc[0][1] = MFMA(kf1[2*ksl+0], qf[1][4+ksl], sacc[0][1]);
            sacc[1][0] = MFMA(kf1[2*ksl+1], qf[0][4+ksl], sacc[1][0]);
            sacc[1][1] = MFMA(kf1[2*ksl+1], qf[1][4+ksl], sacc[1][1]);
        }
        float ex[2][2][4];
        #pragma unroll
        for (int mt = 0; mt < 2; ++mt)
            #pragma unroll
            for (int nt = 0; nt < 2; ++nt)
                #pragma unroll
                for (int r = 0; r < 4; ++r)
                    ex[mt][nt][r] = __expf(0.0625f * sacc[mt][nt][r]);
        #pragma unroll
        for (int nt = 0; nt < 2; ++nt)
            #pragma unroll
            for (int mt = 0; mt < 2; ++mt)
                #pragma unroll
                for (int r = 0; r < 4; ++r) rAcc[nt] += ex[mt][nt][r];
        // C partial: reduce this wave's 32 n (nt regs + shfl over l15), store
        #pragma unroll
        for (int mt = 0; mt < 2; ++mt)
            #pragma unroll
            for (int r = 0; r < 4; ++r) {
                float cp = ex[mt][0][r] + ex[mt][1][r];
                cp += __shfl_xor(cp, 1, 16);
                cp += __shfl_xor(cp, 2, 16);
                cp += __shfl_xor(cp, 4, 16);
                cp += __shfl_xor(cp, 8, 16);
                if (l15 == 0)
                    cpart[m0 + (2*wm+mt)*16 + quad*4 + r] = cp;
            }
    }
    // R: shfl reduces quad; cross-wm combine via LDS; wm==0 writes the slot.
    #pragma unroll
    for (int nt = 0; nt < 2; ++nt) {
        float rp = rAcc[nt];
        rp += __shfl_xor(rp, 16, 64);
        rp += __shfl_xor(rp, 32, 64);
        if (quad == 0) rbuf[wm][nt][wn*32 + l15] = rp;
    }
    __syncthreads();
    #pragma unroll
    for (int nt = 0; nt < 2; ++nt) {
        if (quad == 0 && wm == 0) {
            float tot = rbuf[0][nt][wn*32 + l15] + rbuf[1][nt][wn*32 + l15];
            R_part[(size_t)mhalf*BHn*Nn + (size_t)bh*Nn + n0 + (2*wn+nt)*16 + l15] = tot;
        }
    }
}

// ---------------------------------------------------------------------------
// K2b: iR = 1/sum(R_part over 2), iC = 1/sum(C_part over 96)
// ---------------------------------------------------------------------------
__global__ void inv_kernel(const float* __restrict__ R_part,
                           const float* __restrict__ C_part,
                           float* __restrict__ iR, float* __restrict__ iC) {
    int i = blockIdx.x * blockDim.x + threadIdx.x;   // over BHn*Nn
    float r = R_part[i] + R_part[(size_t)BHn*Nn + i];
    float c = 0.f;
    for (int s = 0; s < 96; ++s)
        c += C_part[(size_t)s*BHn*Nn + i];
    iR[i] = 1.0f / r;
    iC[i] = 1.0f / c;
}

// ---------------------------------------------------------------------------
// K3 v7: f1aT[e][n] = invR[n]*sum_m exp(0.125*raw)*invC[m]*vT[e][m]
// LDS = double-buffered Ps ONLY (17.4 KB; 1 barrier/chunk). K via the same
// half-chunk double-buffered register pipeline as rc (kf0/kf1, direct
// global, L2-resident). Q-frags direct global once; V-frags batch-loaded
// at chunk top (R8-proven). Cycle model: LDS-port/chunk-block drops
// 1632 -> 480 cyc, so the port stops being the ~5x-dominant pipe.
// NOTE: et loops MUST have compile-time trip counts with wave-uniform guards;
// a runtime trip count demotes acc[][] to scratch (3 GB of HBM writes, R2 bug).
// ---------------------------------------------------------------------------
__global__ __launch_bounds__(256, 2) void f1a_mfma(const u16* __restrict__ qh,
                                                   const u16* __restrict__ kh,
                                                   const u16* __restrict__ vT,
                                                   const float* __restrict__ iR,
                                                   const float* __restrict__ iC,
                                                   u16* __restrict__ f1aT) {
    __shared__ u16 Ps[2][64*68];                // 17408 B total
    int tid = threadIdx.x;
    int w = tid >> 6, lane = tid & 63, quad = lane >> 4, l15 = lane & 15;
    int bh = blockIdx.y, n0 = blockIdx.x * 64;
    const u16* qp = qh + ((size_t)bh*Nn + n0)*HDn;
    const u16* kp = kh + (size_t)bh*Nn*HDn;
    const u16* vp = vT + (size_t)bh*EP*Nn;
    int wm = w & 1, wn = w >> 1;

    // Q-fragments direct from global (once per block)
    bf16x8 qf[2][8];
    #pragma unroll
    for (int nt = 0; nt < 2; ++nt)
        #pragma unroll
        for (int ks = 0; ks < 8; ++ks)
            qf[nt][ks] = *(const bf16x8*)(qp
                + (size_t)((2*wn+nt)*16 + l15)*HDn + ks*32 + quad*8);

    // per-wave K row bases
    const u16* ka = kp + (size_t)((2*wm+0)*16 + l15)*HDn + quad*8;
    const u16* kb = kp + (size_t)((2*wm+1)*16 + l15)*HDn + quad*8;
    bf16x8 kf0[8], kf1[8];
    #pragma unroll
    for (int ksl = 0; ksl < 4; ++ksl) {         // init: chunk 0, half 0
        kf0[2*ksl+0] = *(const bf16x8*)(ka + ksl*32);
        kf0[2*ksl+1] = *(const bf16x8*)(kb + ksl*32);
    }

    const int et0 = w*4;        // wave w owns e-tiles et0..et0+3; wave 3 also 16
    f32x4 acc[4][5];
    #pragma unroll
    for (int a = 0; a < 4; ++a)
        #pragma unroll
        for (int b = 0; b < 5; ++b) acc[a][b] = (f32x4){0.f,0.f,0.f,0.f};

    for (int mc = 0; mc < Nn/64; ++mc) {
        int m0 = mc * 64;
        int m0n = (mc + 1 < Nn/64) ? (mc + 1)*64 : 0;   // clamped next chunk
        u16* psb = &Ps[mc & 1][0];
        // V fragments for this chunk (batch issue; consumed after S^T+exp)
        bf16x8 vf[2][5];
        #pragma unroll
        for (int ks = 0; ks < 2; ++ks)
            #pragma unroll
            for (int et = 0; et < 5; ++et)
                if (et < 4 || et0 + et == 16)
                    vf[ks][et] = *(const bf16x8*)(vp
                        + (size_t)((et0+et)*16 + l15)*Nn + m0 + ks*32 + quad*8);
        // iC for this wave's m rows (L2-hot)
        float4 ic0 = *(const float4*)(iC + (size_t)bh*Nn + m0 + (2*wm+0)*16 + quad*4);
        float4 ic1 = *(const float4*)(iC + (size_t)bh*Nn + m0 + (2*wm+1)*16 + quad*4);
        f32x4 sacc[2][2];
        #pragma unroll
        for (int i = 0; i < 2; ++i)
            #pragma unroll
            for (int j = 0; j < 2; ++j) sacc[i][j] = (f32x4){0.f,0.f,0.f,0.f};
        // prefetch kf1 <- (m0, half 1)
        #pragma unroll
        for (int ksl = 0; ksl < 4; ++ksl) {
            kf1[2*ksl+0] = *(const bf16x8*)(ka + (size_t)m0*HDn + (4+ksl)*32);
            kf1[2*ksl+1] = *(const bf16x8*)(kb + (size_t)m0*HDn + (4+ksl)*32);
        }
        // S^T half 0 (ks 0..3) with kf0
        #pragma unroll
        for (int ksl = 0; ksl < 4; ++ksl) {
            sacc[0][0] = MFMA(kf0[2*ksl+0], qf[0][ksl], sacc[0][0]);
            sacc[0][1] = MFMA(kf0[2*ksl+0], qf[1][ksl], sacc[0][1]);
            sacc[1][0] = MFMA(kf0[2*ksl+1], qf[0][ksl], sacc[1][0]);
            sacc[1][1] = MFMA(kf0[2*ksl+1], qf[1][ksl], sacc[1][1]);
        }
        // prefetch kf0 <- (next chunk, half 0)
        #pragma unroll
        for (int ksl = 0; ksl < 4; ++ksl) {
            kf0[2*ksl+0] = *(const bf16x8*)(ka + (size_t)m0n*HDn + ksl*32);
            kf0[2*ksl+1] = *(const bf16x8*)(kb + (size_t)m0n*HDn + ksl*32);
        }
        // S^T half 1 (ks 4..7) with kf1
        #pragma unroll
        for (int ksl = 0; ksl < 4; ++ksl) {
            sacc[0][0] = MFMA(kf1[2*ksl+0], qf[0][4+ksl], sacc[0][0]);
            sacc[0][1] = MFMA(kf1[2*ksl+0], qf[1][4+ksl], sacc[0][1]);
            sacc[1][0] = MFMA(kf1[2*ksl+1], qf[0][4+ksl], sacc[1][0]);
            sacc[1][1] = MFMA(kf1[2*ksl+1], qf[1][4+ksl], sacc[1][1]);
        }
        // P = exp(2*S)*invC[m]; pack 4 m-contig bf16, write psb[n][m]
        #pragma unroll
        for (int mt = 0; mt < 2; ++mt)
            #pragma unroll
            for (int nt = 0; nt < 2; ++nt) {
                u16x4 pk;
                #pragma unroll
                for (int r = 0; r < 4; ++r) {
                    float icv = (mt == 0) ? ((const float*)&ic0)[r] : ((const float*)&ic1)[r];
                    pk[r] = f2bf(__expf(0.125f * sacc[mt][nt][r]) * icv);
                }
                int n = (2*wn+nt)*16 + l15;
                int m = (2*wm+mt)*16 + quad*4;
                *(u16x4*)&psb[n*68 + m] = pk;
            }
        __syncthreads();   // RAW: all waves' P ready (dbuf kills the WAR barrier)
        // PV: acc += P · V   (A = psb[n][m] from LDS, B = vf registers)
        #pragma unroll
        for (int ks = 0; ks < 2; ++ks) {
            bf16x8 pa[4];
            #pragma unroll
            for (int nt = 0; nt < 4; ++nt)
                pa[nt] = ld_frag8(&psb[(nt*16 + l15)*68 + ks*32 + quad*8]);
            #pragma unroll
            for (int et = 0; et < 5; ++et) {
                if (et < 4 || et0 + et == 16) {   // wave-uniform; static indices
                    #pragma unroll
                    for (int nt = 0; nt < 4; ++nt)
                        acc[nt][et] = MFMA(pa[nt], vf[ks][et], acc[nt][et]);
                }
            }
        }
    }
    // epilogue: scale by invR[n], pack bf16, store transposed f1aT[e][n]
    #pragma unroll
    for (int nt = 0; nt < 4; ++nt) {
        float4 ir4 = *(const float4*)(iR + (size_t)bh*Nn + n0 + nt*16 + quad*4);
        #pragma unroll
        for (int et = 0; et < 5; ++et) {
            if (et < 4 || et0 + et == 16) {
                int e = (et0+et)*16 + l15;
                u16x4 ov;
                #pragma unroll
                for (int r = 0; r < 4; ++r)
                    ov[r] = f2bf(acc[nt][et][r] * ((const float*)&ir4)[r]);
                *(u16x4*)(f1aT + ((size_t)bh*EP + e)*Nn + n0 + nt*16 + quad*4) = ov;
            }
        }
    }
}

// ---------------------------------------------------------------------------
// K4: fund[d,e] = sum_n vT[d][n] * f1aT[e][n]  via MFMA (K=3072)
// ---------------------------------------------------------------------------
__global__ __launch_bounds__(256) void fund_mfma(const u16* __restrict__ vT,
                                                 const u16* __restrict__ f1aT,
                                                 float* __restrict__ fund) {
    __shared__ u16 At[64*136];
    __shared__ u16 Bt[64*136];
    int tid = threadIdx.x;
    int w = tid >> 6, lane = tid & 63, quad = lane >> 4, l15 = lane & 15;
    int bh = blockIdx.z;
    int d0 = blockIdx.y * 64, e0 = blockIdx.x * 64;
    const u16* ap = vT   + (size_t)bh*EP*Nn;
    const u16* bp = f1aT + (size_t)bh*EP*Nn;
    int wd = w & 1, we = w >> 1;
    const u16x8 zero8 = {0,0,0,0,0,0,0,0};

    f32x4 acc[2][2];
    #pragma unroll
    for (int i = 0; i < 2; ++i)
        #pragma unroll
        for (int j = 0; j < 2; ++j) acc[i][j] = (f32x4){0.f,0.f,0.f,0.f};

    for (int nc = 0; nc < Nn; nc += 128) {
        __syncthreads();
        #pragma unroll
        for (int i = 0; i < 4; ++i) {
            int u = tid + i*256;
            int row = u >> 4, seg = u & 15;
            int da = d0 + row, eb = e0 + row;
            *(u16x8*)&At[row*136 + seg*8] = (da < EP)
                ? *(const u16x8*)(ap + (size_t)da*Nn + nc + seg*8) : zero8;
            *(u16x8*)&Bt[row*136 + seg*8] = (eb < EP)
                ? *(const u16x8*)(bp + (size_t)eb*Nn + nc + seg*8) : zero8;
        }
        __syncthreads();
        #pragma unroll
        for (int ks = 0; ks < 4; ++ks) {
            bf16x8 a0 = ld_frag16(&At[((2*wd+0)*16 + l15)*136 + ks*32 + quad*8]);
            bf16x8 a1 = ld_frag16(&At[((2*wd+1)*16 + l15)*136 + ks*32 + quad*8]);
            bf16x8 b0 = ld_frag16(&Bt[((2*we+0)*16 + l15)*136 + ks*32 + quad*8]);
            bf16x8 b1 = ld_frag16(&Bt[((2*we+1)*16 + l15)*136 + ks*32 + quad*8]);
            acc[0][0] = MFMA(a0, b0, acc[0][0]);
            acc[0][1] = MFMA(a0, b1, acc[0][1]);
            acc[1][0] = MFMA(a1, b0, acc[1][0]);
            acc[1][1] = MFMA(a1, b1, acc[1][1]);
        }
    }
    #pragma unroll
    for (int dt = 0; dt < 2; ++dt)
        #pragma unroll
        for (int et = 0; et < 2; ++et)
            #pragma unroll
            for (int r = 0; r < 4; ++r) {
                int d = d0 + (2*wd+dt)*16 + quad*4 + r;
                int e = e0 + (2*we+et)*16 + l15;
                if (d < Dn && e < Dn)
                    fund[(size_t)bh*Dn*Dn + (size_t)d*Dn + e] = acc[dt][et][r];
            }
}

// ---------------------------------------------------------------------------
// K5: out[b,d2,o] = sum_{h,d1} fund[b,h,d1,d2] * W_pf[o, h*262+d1] + b_pf[o]
// ---------------------------------------------------------------------------
__global__ __launch_bounds__(256) void out_gemm(const float* __restrict__ fund,
                                                const float* __restrict__ Wpf,
                                                const float* __restrict__ bpf,
                                                float* __restrict__ out) {
    __shared__ float As[16][68];
    __shared__ float Bs[16][68];
    int tid = threadIdx.x;
    int b_ = blockIdx.z;
    int d2b = blockIdx.y * 64, ob = blockIdx.x * 64;
    int ty = tid >> 4, tx = tid & 15;
    int arow = tid >> 4, ac4 = (tid & 15) << 2;
    int brow = tid >> 2, bj4 = (tid & 3) << 2;
    float acc[4][4] = {};

    for (int jc = 0; jc < 786; jc += 16) {
        int j = jc + arow;
        int h  = j / Dn;
        int d1 = j - h*Dn;
        #pragma unroll
        for (int jj = 0; jj < 4; ++jj) {
            int d2 = d2b + ac4 + jj;
            float v = 0.0f;
            if (j < 786 && d2 < Dn)
                v = fund[((size_t)(b_*Hn + h)*Dn + d1)*Dn + d2];
            As[arow][ac4+jj] = v;
        }
        #pragma unroll
        for (int jj = 0; jj < 4; ++jj) {
            int j2 = jc + bj4 + jj;
            Bs[bj4+jj][brow] = (j2 < 786) ? Wpf[(size_t)(ob + brow)*786 + j2] : 0.0f;
        }
        __syncthreads();
        #pragma unroll
        for (int kk = 0; kk < 16; ++kk) {
            float a[4], b[4];
            #pragma unroll
            for (int i = 0; i < 4; ++i) a[i] = As[kk][ty*4+i];
            #pragma unroll
            for (int j2 = 0; j2 < 4; ++j2) b[j2] = Bs[kk][tx*4+j2];
            #pragma unroll
            for (int i = 0; i < 4; ++i)
                #pragma unroll
                for (int j2 = 0; j2 < 4; ++j2) acc[i][j2] += a[i]*b[j2];
        }
        __syncthreads();
    }
    #pragma unroll
    for (int i = 0; i < 4; ++i) {
        int d2 = d2b + ty*4 + i;
        if (d2 >= Dn) continue;
        #pragma unroll
        for (int j = 0; j < 4; ++j) {
            int o = ob + tx*4 + j;
            out[((size_t)b_*Dn + d2)*DIMn + o] = acc[i][j] + bpf[o];
        }
    }
}

// ---------------------------------------------------------------------------
extern "C" void kernel_launch(void* const* d_in, const int* in_sizes, int n_in,
                              void* d_out, int out_size, void* d_ws, size_t ws_size,
                              hipStream_t stream) {
    const float* x    = (const float*)d_in[0];   // [4,3072,768]
    const float* Wqkv = (const float*)d_in[1];   // [2304,768]
    const float* Wpf  = (const float*)d_in[2];   // [768,786]
    const float* bpf  = (const float*)d_in[3];   // [768]
    float* out = (float*)d_out;                  // [4,262,768]

    char* p = (char*)d_ws;
    u16* qh    = (u16*)p;                       p += (size_t)BHn*Nn*HDn*2;   // 18.87 MB
    u16* kh    = (u16*)p;                       p += (size_t)BHn*Nn*HDn*2;   // 18.87 MB
    u16* vT    = (u16*)p;                       p += (size_t)BHn*EP*Nn*2;    // 20.05 MB
    u16* f1aT  = (u16*)p;                       p += (size_t)BHn*EP*Nn*2;    // 20.05 MB
    u16* xb    = (u16*)p;                       p += (size_t)Bn*Nn*DIMn*2;   // 18.87 MB
    u16* Wb    = (u16*)p;                       p += (size_t)3*DIMn*DIMn*2;  // 3.54 MB
    float* Rp  = (float*)p;                     p += (size_t)2*BHn*Nn*4;     // 288 KB
    float* Cp  = (float*)p;                     p += (size_t)96*BHn*Nn*4;    // 14.16 MB
    float* iR  = (float*)p;                     p += (size_t)BHn*Nn*4;
    float* iC  = (float*)p;                     p += (size_t)BHn*Nn*4;
    float* fund= (float*)p;                     p += (size_t)BHn*Dn*Dn*4;    // 3.29 MB

    to_bf16  <<<dim3((Bn*Nn*DIMn/8 + 255)/256), 256, 0, stream>>>(x, xb, Bn*Nn*DIMn/8);
    to_bf16  <<<dim3((3*DIMn*DIMn/8 + 255)/256), 256, 0, stream>>>(Wqkv, Wb, 3*DIMn*DIMn/8);
    qkv_mfma <<<dim3(36, 192), 256, 0, stream>>>(xb, Wb, qh, kh, vT);
    pos_fill <<<dim3(BHn*16*Nn/256), 256, 0, stream>>>(vT);
    rc_mfma  <<<dim3(2, Nn/64, BHn), 256, 0, stream>>>(qh, kh, Rp, Cp);
    inv_kernel<<<dim3(BHn*Nn/256), 256, 0, stream>>>(Rp, Cp, iR, iC);
    f1a_mfma <<<dim3(Nn/64, BHn), 256, 0, stream>>>(qh, kh, vT, iR, iC, f1aT);
    fund_mfma<<<dim3(5, 5, BHn), 256, 0, stream>>>(vT, f1aT, fund);
    out_gemm <<<dim3(DIMn/64, 5, Bn), 256, 0, stream>>>(fund, Wpf, bpf, out);
}

// Round 11
// 757.331 us; speedup vs baseline: 1.6703x; 1.6703x over previous
//
#include <hip/hip_runtime.h>

typedef unsigned short u16;
typedef u16 u16x8 __attribute__((ext_vector_type(8)));
typedef u16 u16x4 __attribute__((ext_vector_type(4)));
typedef __bf16 bf16x8 __attribute__((ext_vector_type(8)));
typedef float f32x4 __attribute__((ext_vector_type(4)));

#define Bn   4
#define Nn   3072
#define DIMn 768
#define Hn   3
#define HDn  256
#define BHn  12
#define Dn   262
#define EP   272      // e-rows padded to 17*16

__device__ __forceinline__ u16 f2bf(float f) {
    unsigned u = __builtin_bit_cast(unsigned, f);
    u += 0x7fffu + ((u >> 16) & 1u);
    return (u16)(u >> 16);
}
__device__ __forceinline__ float bf2f(u16 h) {
    unsigned u = ((unsigned)h) << 16;
    return __builtin_bit_cast(float, u);
}
__device__ __forceinline__ bf16x8 ld_frag16(const u16* p) {   // 16B-aligned read
    return *(const bf16x8*)p;
}
__device__ __forceinline__ bf16x8 ld_frag8(const u16* p) {    // 8B-aligned (2x b64)
    union { u16x4 h[2]; bf16x8 v; } u;
    u.h[0] = *(const u16x4*)p;
    u.h[1] = *(const u16x4*)(p + 4);
    return u.v;
}
#define MFMA(a,b,c) __builtin_amdgcn_mfma_f32_16x16x32_bf16(a, b, c, 0, 0, 0)

// ---------------------------------------------------------------------------
// K0: fp32 -> bf16 elementwise (x and W pre-conversion)
// ---------------------------------------------------------------------------
__global__ void to_bf16(const float* __restrict__ in, u16* __restrict__ out, int n8) {
    int i = blockIdx.x * blockDim.x + threadIdx.x;
    if (i >= n8) return;
    float4 a = *(const float4*)(in + (size_t)i*8);
    float4 b = *(const float4*)(in + (size_t)i*8 + 4);
    u16x8 o;
    o[0]=f2bf(a.x); o[1]=f2bf(a.y); o[2]=f2bf(a.z); o[3]=f2bf(a.w);
    o[4]=f2bf(b.x); o[5]=f2bf(b.y); o[6]=f2bf(b.z); o[7]=f2bf(b.w);
    *(u16x8*)(out + (size_t)i*8) = o;
}

// ---------------------------------------------------------------------------
// K1: qkv = x @ W_qkv^T via MFMA (bf16 inputs, register-prefetch pipeline).
// Writes qh/kh bf16 [bh][n][256] and vT bf16 [bh][272][3072] (transposed).
// ---------------------------------------------------------------------------
__global__ __launch_bounds__(256) void qkv_mfma(const u16* __restrict__ xb,
                                                const u16* __restrict__ Wb,
                                                u16* __restrict__ qh,
                                                u16* __restrict__ kh,
                                                u16* __restrict__ vT) {
    __shared__ u16 Xs[64*72];
    __shared__ u16 Ws[64*72];
    __shared__ u16 Cs[64*72];
    int tid = threadIdx.x;
    int w = tid >> 6, lane = tid & 63, quad = lane >> 4, l15 = lane & 15;
    int cb = blockIdx.x, rb = blockIdx.y;
    int r0 = rb * 64;
    int b_ = rb / 48;
    int n0 = (rb % 48) * 64;
    int which = cb / 12;             // 0:q 1:k 2:v
    int c0l = (cb % 12) * 64;        // col base within 768
    int h = c0l >> 8, hd0 = c0l & 255;
    int bh = b_ * Hn + h;
    int wr = w >> 1, wc = w & 1;
    const u16* xp = xb + (size_t)r0*DIMn;
    const u16* wp = Wb + (size_t)(which*768 + c0l)*DIMn;
    const int sr = tid >> 3, ssg = tid & 7;     // staging: rows sr+32i, seg ssg

    u16x8 xreg[2], wreg[2];
    #pragma unroll
    for (int i = 0; i < 2; ++i) {
        xreg[i] = *(const u16x8*)(xp + (size_t)(sr + 32*i)*DIMn + ssg*8);
        wreg[i] = *(const u16x8*)(wp + (size_t)(sr + 32*i)*DIMn + ssg*8);
    }

    f32x4 acc[2][2];
    #pragma unroll
    for (int i = 0; i < 2; ++i)
        #pragma unroll
        for (int j = 0; j < 2; ++j) acc[i][j] = (f32x4){0.f,0.f,0.f,0.f};

    for (int k0 = 0; k0 < DIMn; k0 += 64) {
        int k0n = (k0 + 64 < DIMn) ? k0 + 64 : 0;
        __syncthreads();
        #pragma unroll
        for (int i = 0; i < 2; ++i) {
            *(u16x8*)&Xs[(sr + 32*i)*72 + ssg*8] = xreg[i];
            *(u16x8*)&Ws[(sr + 32*i)*72 + ssg*8] = wreg[i];
        }
        __syncthreads();
        #pragma unroll
        for (int i = 0; i < 2; ++i) {
            xreg[i] = *(const u16x8*)(xp + (size_t)(sr + 32*i)*DIMn + k0n + ssg*8);
            wreg[i] = *(const u16x8*)(wp + (size_t)(sr + 32*i)*DIMn + k0n + ssg*8);
        }
        #pragma unroll
        for (int ks = 0; ks < 2; ++ks) {
            bf16x8 a0 = ld_frag16(&Xs[(wr*32 +  0 + l15)*72 + ks*32 + quad*8]);
            bf16x8 a1 = ld_frag16(&Xs[(wr*32 + 16 + l15)*72 + ks*32 + quad*8]);
            bf16x8 b0 = ld_frag16(&Ws[(wc*32 +  0 + l15)*72 + ks*32 + quad*8]);
            bf16x8 b1 = ld_frag16(&Ws[(wc*32 + 16 + l15)*72 + ks*32 + quad*8]);
            acc[0][0] = MFMA(a0, b0, acc[0][0]);
            acc[0][1] = MFMA(a0, b1, acc[0][1]);
            acc[1][0] = MFMA(a1, b0, acc[1][0]);
            acc[1][1] = MFMA(a1, b1, acc[1][1]);
        }
    }
    __syncthreads();
    // write C tiles to Cs (transposed for v)
    #pragma unroll
    for (int rt = 0; rt < 2; ++rt)
        #pragma unroll
        for (int ct = 0; ct < 2; ++ct)
            #pragma unroll
            for (int r = 0; r < 4; ++r) {
                int row = wr*32 + rt*16 + quad*4 + r;
                int col = wc*32 + ct*16 + l15;
                u16 v = f2bf(acc[rt][ct][r]);
                if (which < 2) Cs[row*72 + col] = v;
                else           Cs[col*72 + row] = v;
            }
    __syncthreads();
    #pragma unroll
    for (int i = 0; i < 2; ++i) {
        int u = tid + i*256;
        int row = u >> 3, seg = u & 7;
        u16x8 vv = *(const u16x8*)&Cs[row*72 + seg*8];
        if (which == 0)
            *(u16x8*)(qh + ((size_t)bh*Nn + n0 + row)*HDn + hd0 + seg*8) = vv;
        else if (which == 1)
            *(u16x8*)(kh + ((size_t)bh*Nn + n0 + row)*HDn + hd0 + seg*8) = vv;
        else
            *(u16x8*)(vT + ((size_t)bh*EP + hd0 + row)*Nn + n0 + seg*8) = vv;
    }
}

// ---------------------------------------------------------------------------
// K1b: positional rows 256..261 of vT; rows 262..271 get zero.
// ---------------------------------------------------------------------------
__global__ void pos_fill(u16* __restrict__ vT) {
    int idx = blockIdx.x * blockDim.x + threadIdx.x;   // over BH*16*N
    int bh = idx / (16*Nn);
    int rem = idx - bh*16*Nn;
    int row = rem / Nn;        // 0..15
    int n = rem - row*Nn;
    int gy = n % 48, gx = n / 48;
    float p3 = -1.0f + (2.0f/47.0f)*gy;
    float p4 = -1.0f + (2.0f/63.0f)*gx;
    float v = 0.f;
    if (row == 0) v = p3*p3;
    else if (row == 1) v = p4*p4;
    else if (row == 2) v = p3*p4;
    else if (row == 3) v = p3;
    else if (row == 4) v = p4;
    else if (row == 5) v = 1.0f;
    vT[((size_t)bh*EP + 256 + row)*Nn + n] = f2bf(v);
}

// ---------------------------------------------------------------------------
// K2 (R6 version — best measured): atomic-free R/C partials + K register-
// prefetch through LDS. R_part[mhalf][bh][n] exclusive per block;
// C_part[nb*2+wn][bh][m] exclusive per (block, wn-wave-pair).
// ---------------------------------------------------------------------------
__global__ __launch_bounds__(256) void rc_mfma(const u16* __restrict__ qh,
                                               const u16* __restrict__ kh,
                                               float* __restrict__ R_part,
                                               float* __restrict__ C_part) {
    __shared__ u16 Ks[64*264];            // doubles as Q staging during preload
    __shared__ float rbuf[2][2][64];      // [wm][nt][wn*32 + l15]
    int tid = threadIdx.x;
    int w = tid >> 6, lane = tid & 63, quad = lane >> 4, l15 = lane & 15;
    int bh = blockIdx.z;
    int nb = blockIdx.y;
    int n0 = nb * 64;
    int mhalf = blockIdx.x;               // 0 or 1
    const u16* qp = qh + ((size_t)bh*Nn + n0)*HDn;
    const u16* kp = kh + (size_t)bh*Nn*HDn;
    int wm = w & 1, wn = w >> 1;

    // stage Q tile into Ks region, preload fragments, then overwrite with K
    #pragma unroll
    for (int i = 0; i < 8; ++i) {
        int e = tid + i*256;
        int row = e >> 5, seg = e & 31;
        *(u16x8*)&Ks[row*264 + seg*8] = *(const u16x8*)(qp + (size_t)row*HDn + seg*8);
    }
    __syncthreads();
    bf16x8 qf[2][8];
    #pragma unroll
    for (int nt = 0; nt < 2; ++nt)
        #pragma unroll
        for (int ks = 0; ks < 8; ++ks)
            qf[nt][ks] = ld_frag16(&Ks[((2*wn+nt)*16 + l15)*264 + ks*32 + quad*8]);

    const int kr = tid >> 5, ksg = tid & 31;
    u16x8 kreg[8];
    #pragma unroll
    for (int i = 0; i < 8; ++i)
        kreg[i] = *(const u16x8*)(kp + (size_t)(mhalf*(Nn/2) + kr + 8*i)*HDn + ksg*8);

    // exclusive C slot for this block's wn wave-pair
    float* cpart = C_part + ((size_t)(nb*2 + wn)*BHn + bh)*Nn;
    float rAcc[2] = {0.f, 0.f};
    for (int mc = 0; mc < Nn/128; ++mc) {
        int m0 = mhalf*(Nn/2) + mc*64;
        int m0n = mhalf*(Nn/2) + ((mc + 1 < Nn/128) ? (mc + 1)*64 : 0);
        __syncthreads();       // qf reads (mc=0) / previous MFMA reads done
        #pragma unroll
        for (int i = 0; i < 8; ++i)
            *(u16x8*)&Ks[(kr + 8*i)*264 + ksg*8] = kreg[i];
        __syncthreads();
        #pragma unroll
        for (int i = 0; i < 8; ++i)
            kreg[i] = *(const u16x8*)(kp + (size_t)(m0n + kr + 8*i)*HDn + ksg*8);
        f32x4 sacc[2][2];
        #pragma unroll
        for (int i = 0; i < 2; ++i)
            #pragma unroll
            for (int j = 0; j < 2; ++j) sacc[i][j] = (f32x4){0.f,0.f,0.f,0.f};
        #pragma unroll
        for (int ks = 0; ks < 8; ++ks) {
            bf16x8 a0 = ld_frag16(&Ks[((2*wm+0)*16 + l15)*264 + ks*32 + quad*8]);
            bf16x8 a1 = ld_frag16(&Ks[((2*wm+1)*16 + l15)*264 + ks*32 + quad*8]);
            sacc[0][0] = MFMA(a0, qf[0][ks], sacc[0][0]);
            sacc[0][1] = MFMA(a0, qf[1][ks], sacc[0][1]);
            sacc[1][0] = MFMA(a1, qf[0][ks], sacc[1][0]);
            sacc[1][1] = MFMA(a1, qf[1][ks], sacc[1][1]);
        }
        float ex[2][2][4];
        #pragma unroll
        for (int mt = 0; mt < 2; ++mt)
            #pragma unroll
            for (int nt = 0; nt < 2; ++nt)
                #pragma unroll
                for (int r = 0; r < 4; ++r)
                    ex[mt][nt][r] = __expf(0.0625f * sacc[mt][nt][r]);
        #pragma unroll
        for (int nt = 0; nt < 2; ++nt)
            #pragma unroll
            for (int mt = 0; mt < 2; ++mt)
                #pragma unroll
                for (int r = 0; r < 4; ++r) rAcc[nt] += ex[mt][nt][r];
        // C partial: reduce this wave's 32 n (nt regs + shfl over l15), store
        #pragma unroll
        for (int mt = 0; mt < 2; ++mt)
            #pragma unroll
            for (int r = 0; r < 4; ++r) {
                float cp = ex[mt][0][r] + ex[mt][1][r];
                cp += __shfl_xor(cp, 1, 16);
                cp += __shfl_xor(cp, 2, 16);
                cp += __shfl_xor(cp, 4, 16);
                cp += __shfl_xor(cp, 8, 16);
                if (l15 == 0)
                    cpart[m0 + (2*wm+mt)*16 + quad*4 + r] = cp;
            }
    }
    // R: shfl reduces quad; cross-wm combine via LDS; wm==0 writes the slot.
    #pragma unroll
    for (int nt = 0; nt < 2; ++nt) {
        float rp = rAcc[nt];
        rp += __shfl_xor(rp, 16, 64);
        rp += __shfl_xor(rp, 32, 64);
        if (quad == 0) rbuf[wm][nt][wn*32 + l15] = rp;
    }
    __syncthreads();
    #pragma unroll
    for (int nt = 0; nt < 2; ++nt) {
        if (quad == 0 && wm == 0) {
            float tot = rbuf[0][nt][wn*32 + l15] + rbuf[1][nt][wn*32 + l15];
            R_part[(size_t)mhalf*BHn*Nn + (size_t)bh*Nn + n0 + (2*wn+nt)*16 + l15] = tot;
        }
    }
}

// ---------------------------------------------------------------------------
// K2b: iR = 1/sum(R_part over 2), iC = 1/sum(C_part over 96)
// ---------------------------------------------------------------------------
__global__ void inv_kernel(const float* __restrict__ R_part,
                           const float* __restrict__ C_part,
                           float* __restrict__ iR, float* __restrict__ iC) {
    int i = blockIdx.x * blockDim.x + threadIdx.x;   // over BHn*Nn
    float r = R_part[i] + R_part[(size_t)BHn*Nn + i];
    float c = 0.f;
    for (int s = 0; s < 96; ++s)
        c += C_part[(size_t)s*BHn*Nn + i];
    iR[i] = 1.0f / r;
    iC[i] = 1.0f / c;
}

// ---------------------------------------------------------------------------
// K3 (R6 version + et-guard fix): f1aT[e][n] =
//     invR[n]*sum_m exp(0.125*raw)*invC[m]*vT[e][m]
// K register-prefetch into LDS; Vt staged in LDS; Ps roundtrip; Q-frags in
// regs via Bpool overlay. Guard FIXED to (et<4 || et0+et==16): the old
// (et0+et<17) made waves 0-2 redundantly recompute e-tiles 4/8/12
// (+15% PV MFMA and +15% Vt LDS reads; correct but wasted — R8-validated).
// NOTE: et loops MUST have compile-time trip counts with wave-uniform guards;
// a runtime trip count demotes acc[][] to scratch (3 GB of HBM writes, R2 bug).
// Structure is latency-bound (all pipes <20%): 3 barriers/chunk, occupancy
// AGPR-capped at 2 blocks/CU. Register-K variants spill (R10); LDS-diet
// variants expose L2 latency (R7). This is the measured sweet spot.
// ---------------------------------------------------------------------------
__global__ __launch_bounds__(256, 2) void f1a_mfma(const u16* __restrict__ qh,
                                                   const u16* __restrict__ kh,
                                                   const u16* __restrict__ vT,
                                                   const float* __restrict__ iR,
                                                   const float* __restrict__ iC,
                                                   u16* __restrict__ f1aT) {
    __shared__ u16 Ks[64*264];                  // 33792 B
    __shared__ u16 Bpool[EP*72 + 64*68];        // Vt(39168B) + Ps(8704B)
    u16* Vt = Bpool;
    u16* Ps = Bpool + EP*72;
    u16* Qs = Bpool;                            // overlay during preload
    int tid = threadIdx.x;
    int w = tid >> 6, lane = tid & 63, quad = lane >> 4, l15 = lane & 15;
    int bh = blockIdx.y, n0 = blockIdx.x * 64;
    const u16* qp = qh + ((size_t)bh*Nn + n0)*HDn;
    const u16* kp = kh + (size_t)bh*Nn*HDn;
    const u16* vp = vT + (size_t)bh*EP*Nn;
    int wm = w & 1, wn = w >> 1;

    // stage Q tile (Bpool overlay) and preload Q-fragments into registers
    #pragma unroll
    for (int i = 0; i < 8; ++i) {
        int e = tid + i*256;
        int row = e >> 5, seg = e & 31;
        *(u16x8*)&Qs[row*264 + seg*8] = *(const u16x8*)(qp + (size_t)row*HDn + seg*8);
    }
    __syncthreads();
    bf16x8 qf[2][8];
    #pragma unroll
    for (int nt = 0; nt < 2; ++nt)
        #pragma unroll
        for (int ks = 0; ks < 8; ++ks)
            qf[nt][ks] = ld_frag16(&Qs[((2*wn+nt)*16 + l15)*264 + ks*32 + quad*8]);

    // prefetch-address decomposition
    const int kr = tid >> 5, ksg = tid & 31;    // K: rows kr+8i, seg ksg
    const int vr = tid >> 3, vsg = tid & 7;     // V: rows vr+32i, seg vsg
    u16x8 kreg[8], vreg[9];
    // prefetch chunk 0
    #pragma unroll
    for (int i = 0; i < 8; ++i)
        kreg[i] = *(const u16x8*)(kp + (size_t)(kr + 8*i)*HDn + ksg*8);
    #pragma unroll
    for (int i = 0; i < 9; ++i)
        if (i < 8 || tid < 128)
            vreg[i] = *(const u16x8*)(vp + (size_t)(vr + 32*i)*Nn + vsg*8);

    const int et0 = w*4;        // wave w owns e-tiles et0..et0+3; wave 3 also 16
    f32x4 acc[4][5];
    #pragma unroll
    for (int a = 0; a < 4; ++a)
        #pragma unroll
        for (int b = 0; b < 5; ++b) acc[a][b] = (f32x4){0.f,0.f,0.f,0.f};

    for (int mc = 0; mc < Nn/64; ++mc) {
        int m0 = mc * 64;
        int m0n = (mc + 1 < Nn/64) ? (mc + 1)*64 : 0;   // clamped next chunk
        __syncthreads();   // qf/prev-PV readers of Bpool + Ks done
        // write prefetched chunk into LDS
        #pragma unroll
        for (int i = 0; i < 8; ++i)
            *(u16x8*)&Ks[(kr + 8*i)*264 + ksg*8] = kreg[i];
        #pragma unroll
        for (int i = 0; i < 9; ++i)
            if (i < 8 || tid < 128)
                *(u16x8*)&Vt[(vr + 32*i)*72 + vsg*8] = vreg[i];
        __syncthreads();
        // issue prefetch for next chunk (overlaps all compute below)
        #pragma unroll
        for (int i = 0; i < 8; ++i)
            kreg[i] = *(const u16x8*)(kp + (size_t)(m0n + kr + 8*i)*HDn + ksg*8);
        #pragma unroll
        for (int i = 0; i < 9; ++i)
            if (i < 8 || tid < 128)
                vreg[i] = *(const u16x8*)(vp + (size_t)(vr + 32*i)*Nn + m0n + vsg*8);
        // iC for this wave's m rows (L2-hot)
        float4 ic0 = *(const float4*)(iC + (size_t)bh*Nn + m0 + (2*wm+0)*16 + quad*4);
        float4 ic1 = *(const float4*)(iC + (size_t)bh*Nn + m0 + (2*wm+1)*16 + quad*4);
        // S^T = K·Q^T  (C rows = m, cols = n)
        f32x4 sacc[2][2];
        #pragma unroll
        for (int i = 0; i < 2; ++i)
            #pragma unroll
            for (int j = 0; j < 2; ++j) sacc[i][j] = (f32x4){0.f,0.f,0.f,0.f};
        #pragma unroll
        for (int ks = 0; ks < 8; ++ks) {
            bf16x8 a0 = ld_frag16(&Ks[((2*wm+0)*16 + l15)*264 + ks*32 + quad*8]);
            bf16x8 a1 = ld_frag16(&Ks[((2*wm+1)*16 + l15)*264 + ks*32 + quad*8]);
            sacc[0][0] = MFMA(a0, qf[0][ks], sacc[0][0]);
            sacc[0][1] = MFMA(a0, qf[1][ks], sacc[0][1]);
            sacc[1][0] = MFMA(a1, qf[0][ks], sacc[1][0]);
            sacc[1][1] = MFMA(a1, qf[1][ks], sacc[1][1]);
        }
        // P = exp(2*S)*invC[m]; pack 4 m-contig bf16, write Ps[n][m]
        #pragma unroll
        for (int mt = 0; mt < 2; ++mt)
            #pragma unroll
            for (int nt = 0; nt < 2; ++nt) {
                u16x4 pk;
                #pragma unroll
                for (int r = 0; r < 4; ++r) {
                    float icv = (mt == 0) ? ((const float*)&ic0)[r] : ((const float*)&ic1)[r];
                    pk[r] = f2bf(__expf(0.125f * sacc[mt][nt][r]) * icv);
                }
                int n = (2*wn+nt)*16 + l15;
                int m = (2*wm+mt)*16 + quad*4;
                *(u16x4*)&Ps[n*68 + m] = pk;
            }
        __syncthreads();
        // PV: acc += P · V   (A = Ps[n][m], B = Vt[e][m]); fixed guard
        #pragma unroll
        for (int ks = 0; ks < 2; ++ks) {
            bf16x8 pa[4];
            #pragma unroll
            for (int nt = 0; nt < 4; ++nt)
                pa[nt] = ld_frag8(&Ps[(nt*16 + l15)*68 + ks*32 + quad*8]);
            #pragma unroll
            for (int et = 0; et < 5; ++et) {
                if (et < 4 || et0 + et == 16) {   // wave-uniform; static indices
                    bf16x8 vb = ld_frag16(&Vt[((et0+et)*16 + l15)*72 + ks*32 + quad*8]);
                    #pragma unroll
                    for (int nt = 0; nt < 4; ++nt)
                        acc[nt][et] = MFMA(pa[nt], vb, acc[nt][et]);
                }
            }
        }
    }
    // epilogue: scale by invR[n], pack bf16, store transposed f1aT[e][n]
    #pragma unroll
    for (int nt = 0; nt < 4; ++nt) {
        float4 ir4 = *(const float4*)(iR + (size_t)bh*Nn + n0 + nt*16 + quad*4);
        #pragma unroll
        for (int et = 0; et < 5; ++et) {
            if (et < 4 || et0 + et == 16) {
                int e = (et0+et)*16 + l15;
                u16x4 ov;
                #pragma unroll
                for (int r = 0; r < 4; ++r)
                    ov[r] = f2bf(acc[nt][et][r] * ((const float*)&ir4)[r]);
                *(u16x4*)(f1aT + ((size_t)bh*EP + e)*Nn + n0 + nt*16 + quad*4) = ov;
            }
        }
    }
}

// ---------------------------------------------------------------------------
// K4: fund[d,e] = sum_n vT[d][n] * f1aT[e][n]  via MFMA (K=3072)
// ---------------------------------------------------------------------------
__global__ __launch_bounds__(256) void fund_mfma(const u16* __restrict__ vT,
                                                 const u16* __restrict__ f1aT,
                                                 float* __restrict__ fund) {
    __shared__ u16 At[64*136];
    __shared__ u16 Bt[64*136];
    int tid = threadIdx.x;
    int w = tid >> 6, lane = tid & 63, quad = lane >> 4, l15 = lane & 15;
    int bh = blockIdx.z;
    int d0 = blockIdx.y * 64, e0 = blockIdx.x * 64;
    const u16* ap = vT   + (size_t)bh*EP*Nn;
    const u16* bp = f1aT + (size_t)bh*EP*Nn;
    int wd = w & 1, we = w >> 1;
    const u16x8 zero8 = {0,0,0,0,0,0,0,0};

    f32x4 acc[2][2];
    #pragma unroll
    for (int i = 0; i < 2; ++i)
        #pragma unroll
        for (int j = 0; j < 2; ++j) acc[i][j] = (f32x4){0.f,0.f,0.f,0.f};

    for (int nc = 0; nc < Nn; nc += 128) {
        __syncthreads();
        #pragma unroll
        for (int i = 0; i < 4; ++i) {
            int u = tid + i*256;
            int row = u >> 4, seg = u & 15;
            int da = d0 + row, eb = e0 + row;
            *(u16x8*)&At[row*136 + seg*8] = (da < EP)
                ? *(const u16x8*)(ap + (size_t)da*Nn + nc + seg*8) : zero8;
            *(u16x8*)&Bt[row*136 + seg*8] = (eb < EP)
                ? *(const u16x8*)(bp + (size_t)eb*Nn + nc + seg*8) : zero8;
        }
        __syncthreads();
        #pragma unroll
        for (int ks = 0; ks < 4; ++ks) {
            bf16x8 a0 = ld_frag16(&At[((2*wd+0)*16 + l15)*136 + ks*32 + quad*8]);
            bf16x8 a1 = ld_frag16(&At[((2*wd+1)*16 + l15)*136 + ks*32 + quad*8]);
            bf16x8 b0 = ld_frag16(&Bt[((2*we+0)*16 + l15)*136 + ks*32 + quad*8]);
            bf16x8 b1 = ld_frag16(&Bt[((2*we+1)*16 + l15)*136 + ks*32 + quad*8]);
            acc[0][0] = MFMA(a0, b0, acc[0][0]);
            acc[0][1] = MFMA(a0, b1, acc[0][1]);
            acc[1][0] = MFMA(a1, b0, acc[1][0]);
            acc[1][1] = MFMA(a1, b1, acc[1][1]);
        }
    }
    #pragma unroll
    for (int dt = 0; dt < 2; ++dt)
        #pragma unroll
        for (int et = 0; et < 2; ++et)
            #pragma unroll
            for (int r = 0; r < 4; ++r) {
                int d = d0 + (2*wd+dt)*16 + quad*4 + r;
                int e = e0 + (2*we+et)*16 + l15;
                if (d < Dn && e < Dn)
                    fund[(size_t)bh*Dn*Dn + (size_t)d*Dn + e] = acc[dt][et][r];
            }
}

// ---------------------------------------------------------------------------
// K5: out[b,d2,o] = sum_{h,d1} fund[b,h,d1,d2] * W_pf[o, h*262+d1] + b_pf[o]
// ---------------------------------------------------------------------------
__global__ __launch_bounds__(256) void out_gemm(const float* __restrict__ fund,
                                                const float* __restrict__ Wpf,
                                                const float* __restrict__ bpf,
                                                float* __restrict__ out) {
    __shared__ float As[16][68];
    __shared__ float Bs[16][68];
    int tid = threadIdx.x;
    int b_ = blockIdx.z;
    int d2b = blockIdx.y * 64, ob = blockIdx.x * 64;
    int ty = tid >> 4, tx = tid & 15;
    int arow = tid >> 4, ac4 = (tid & 15) << 2;
    int brow = tid >> 2, bj4 = (tid & 3) << 2;
    float acc[4][4] = {};

    for (int jc = 0; jc < 786; jc += 16) {
        int j = jc + arow;
        int h  = j / Dn;
        int d1 = j - h*Dn;
        #pragma unroll
        for (int jj = 0; jj < 4; ++jj) {
            int d2 = d2b + ac4 + jj;
            float v = 0.0f;
            if (j < 786 && d2 < Dn)
                v = fund[((size_t)(b_*Hn + h)*Dn + d1)*Dn + d2];
            As[arow][ac4+jj] = v;
        }
        #pragma unroll
        for (int jj = 0; jj < 4; ++jj) {
            int j2 = jc + bj4 + jj;
            Bs[bj4+jj][brow] = (j2 < 786) ? Wpf[(size_t)(ob + brow)*786 + j2] : 0.0f;
        }
        __syncthreads();
        #pragma unroll
        for (int kk = 0; kk < 16; ++kk) {
            float a[4], b[4];
            #pragma unroll
            for (int i = 0; i < 4; ++i) a[i] = As[kk][ty*4+i];
            #pragma unroll
            for (int j2 = 0; j2 < 4; ++j2) b[j2] = Bs[kk][tx*4+j2];
            #pragma unroll
            for (int i = 0; i < 4; ++i)
                #pragma unroll
                for (int j2 = 0; j2 < 4; ++j2) acc[i][j2] += a[i]*b[j2];
        }
        __syncthreads();
    }
    #pragma unroll
    for (int i = 0; i < 4; ++i) {
        int d2 = d2b + ty*4 + i;
        if (d2 >= Dn) continue;
        #pragma unroll
        for (int j = 0; j < 4; ++j) {
            int o = ob + tx*4 + j;
            out[((size_t)b_*Dn + d2)*DIMn + o] = acc[i][j] + bpf[o];
        }
    }
}

// ---------------------------------------------------------------------------
extern "C" void kernel_launch(void* const* d_in, const int* in_sizes, int n_in,
                              void* d_out, int out_size, void* d_ws, size_t ws_size,
                              hipStream_t stream) {
    const float* x    = (const float*)d_in[0];   // [4,3072,768]
    const float* Wqkv = (const float*)d_in[1];   // [2304,768]
    const float* Wpf  = (const float*)d_in[2];   // [768,786]
    const float* bpf  = (const float*)d_in[3];   // [768]
    float* out = (float*)d_out;                  // [4,262,768]

    char* p = (char*)d_ws;
    u16* qh    = (u16*)p;                       p += (size_t)BHn*Nn*HDn*2;   // 18.87 MB
    u16* kh    = (u16*)p;                       p += (size_t)BHn*Nn*HDn*2;   // 18.87 MB
    u16* vT    = (u16*)p;                       p += (size_t)BHn*EP*Nn*2;    // 20.05 MB
    u16* f1aT  = (u16*)p;                       p += (size_t)BHn*EP*Nn*2;    // 20.05 MB
    u16* xb    = (u16*)p;                       p += (size_t)Bn*Nn*DIMn*2;   // 18.87 MB
    u16* Wb    = (u16*)p;                       p += (size_t)3*DIMn*DIMn*2;  // 3.54 MB
    float* Rp  = (float*)p;                     p += (size_t)2*BHn*Nn*4;     // 288 KB
    float* Cp  = (float*)p;                     p += (size_t)96*BHn*Nn*4;    // 14.16 MB
    float* iR  = (float*)p;                     p += (size_t)BHn*Nn*4;
    float* iC  = (float*)p;                     p += (size_t)BHn*Nn*4;
    float* fund= (float*)p;                     p += (size_t)BHn*Dn*Dn*4;    // 3.29 MB

    to_bf16  <<<dim3((Bn*Nn*DIMn/8 + 255)/256), 256, 0, stream>>>(x, xb, Bn*Nn*DIMn/8);
    to_bf16  <<<dim3((3*DIMn*DIMn/8 + 255)/256), 256, 0, stream>>>(Wqkv, Wb, 3*DIMn*DIMn/8);
    qkv_mfma <<<dim3(36, 192), 256, 0, stream>>>(xb, Wb, qh, kh, vT);
    pos_fill <<<dim3(BHn*16*Nn/256), 256, 0, stream>>>(vT);
    rc_mfma  <<<dim3(2, Nn/64, BHn), 256, 0, stream>>>(qh, kh, Rp, Cp);
    inv_kernel<<<dim3(BHn*Nn/256), 256, 0, stream>>>(Rp, Cp, iR, iC);
    f1a_mfma <<<dim3(Nn/64, BHn), 256, 0, stream>>>(qh, kh, vT, iR, iC, f1aT);
    fund_mfma<<<dim3(5, 5, BHn), 256, 0, stream>>>(vT, f1aT, fund);
    out_gemm <<<dim3(DIMn/64, 5, Bn), 256, 0, stream>>>(fund, Wpf, bpf, out);
}